// Round 6
// baseline (771.406 us; speedup 1.0000x reference)
//
#include <hip/hip_runtime.h>

#define B_ 512
#define T_ 48
#define D_ 128
#define F_ 16
#define H_ 512
// K = D_*F_ = 2048, gates = 4*H_ = 2048, M = T_*B_ = 24576

typedef float f32x4 __attribute__((ext_vector_type(4)));
typedef short s16x8 __attribute__((ext_vector_type(8)));
typedef unsigned short u16x8 __attribute__((ext_vector_type(8)));
typedef unsigned short u16x4 __attribute__((ext_vector_type(4)));
typedef unsigned long long u64;

__device__ __forceinline__ unsigned short f2bf(float x) {
  unsigned u = __float_as_uint(x);
  u += 0x7fffu + ((u >> 16) & 1u);   // round-to-nearest-even
  return (unsigned short)(u >> 16);
}
__device__ __forceinline__ float bf2f(unsigned short h) {
  return __uint_as_float(((unsigned)h) << 16);
}
// fast sigmoid/tanh via v_exp_f32 (exp2) + v_rcp_f32 (~1ulp; adds ~1e-6 rel err)
__device__ __forceinline__ float fsig(float x) {
  float e = __builtin_amdgcn_exp2f(-1.442695041f * x);
  return __builtin_amdgcn_rcpf(1.f + e);
}
__device__ __forceinline__ float ftanh(float x) {
  float e = __builtin_amdgcn_exp2f(2.885390082f * x);
  return 1.f - 2.f * __builtin_amdgcn_rcpf(1.f + e);
}

// Relaxed system-scope (sc0 sc1) accesses: bypass L1/L2, coherent at L3.
__device__ __forceinline__ void st_sys_u64(u64* p, u64 v) {
  __hip_atomic_store(p, v, __ATOMIC_RELAXED, __HIP_MEMORY_SCOPE_SYSTEM);
}
__device__ __forceinline__ u64 ld_sys_u64(const u64* p) {
  return __hip_atomic_load((u64*)p, __ATOMIC_RELAXED, __HIP_MEMORY_SCOPE_SYSTEM);
}
__device__ __forceinline__ void st_sys_u32(unsigned* p, unsigned v) {
  __hip_atomic_store(p, v, __ATOMIC_RELAXED, __HIP_MEMORY_SCOPE_SYSTEM);
}
__device__ __forceinline__ unsigned ld_sys_u32(const unsigned* p) {
  return __hip_atomic_load((unsigned*)p, __ATOMIC_RELAXED, __HIP_MEMORY_SCOPE_SYSTEM);
}

#define AS1 __attribute__((address_space(1)))
#define AS3 __attribute__((address_space(3)))
__device__ __forceinline__ void g2lds16(const void* g, void* l) {
  __builtin_amdgcn_global_load_lds((const AS1 void*)g, (AS3 void*)l, 16, 0, 0);
}

// ---------------- K_prep: fp32 -> bf16 weight conversion ----------------
__global__ __launch_bounds__(256) void k_prep(const float* __restrict__ wih,
                                              const float* __restrict__ whh,
                                              unsigned short* __restrict__ wih_b,
                                              unsigned short* __restrict__ whh_b) {
  long i4 = ((long)blockIdx.x * 256 + threadIdx.x) * 4;
  if (i4 < 4194304) {
    float4 v = *(const float4*)(wih + i4);
    u16x4 o = {f2bf(v.x), f2bf(v.y), f2bf(v.z), f2bf(v.w)};
    *(u16x4*)(wih_b + i4) = o;
  } else {
    long j = i4 - 4194304;
    if (j < 1048576) {
      float4 v = *(const float4*)(whh + j);
      u16x4 o = {f2bf(v.x), f2bf(v.y), f2bf(v.z), f2bf(v.w)};
      *(u16x4*)(whh_b + j) = o;
    }
  }
}

// ---------------- K_ex1: partial e_x sums, full-occupancy streaming -------
// Round-6: old k_ex streamed 192 MB with only 8 waves/CU (latency-bound,
// ~150+ us by subtraction). Now 2048 blocks (b, t-chunk c of 12) x 256 thr
// = 32 waves/CU. Thread = (d, f-half); pair-sum via shfl_xor; partials to
// scratch (reused x_hat region, dead until k_xhat).
__global__ __launch_bounds__(256) void k_ex1(const float* __restrict__ in,
                                             const float* __restrict__ attn_w,
                                             float* __restrict__ e_part) {
  __shared__ float wx[768];
  const int bc = blockIdx.x;            // b*4 + c
  const int b = bc >> 2, c = bc & 3;
  const int tid = threadIdx.x;
  const int d = tid >> 1, fh = tid & 1;
  for (int i = tid; i < 768; i += 256) wx[i] = attn_w[1024 + i];
  __syncthreads();
  const float* base = in + (long)b * 98304 + (long)d * 16 + fh * 8;
  float acc = 0.f;
  for (int t = c * 12; t < c * 12 + 12; ++t) {
    const float4* p = (const float4*)(base + (long)t * 2048);
    float4 v0 = p[0], v1 = p[1];
    const float* wt = wx + fh * 384 + t;
    acc += v0.x * wt[0]   + v0.y * wt[48]  + v0.z * wt[96]  + v0.w * wt[144];
    acc += v1.x * wt[192] + v1.y * wt[240] + v1.z * wt[288] + v1.w * wt[336];
  }
  acc += __shfl_xor(acc, 1);
  if (fh == 0) e_part[(long)bc * 128 + d] = acc;
}

// ---------------- K_ex2: combine partials + softmax over D ---------------
__global__ __launch_bounds__(128) void k_ex2(const float* __restrict__ e_part,
                                             const float* __restrict__ attn_b,
                                             float* __restrict__ a_out) {
  __shared__ float red[128];
  const int b = blockIdx.x, d = threadIdx.x;
  float acc = attn_b[0];
  for (int c = 0; c < 4; ++c) acc += e_part[(long)(b * 4 + c) * 128 + d];
  red[d] = acc;
  __syncthreads();
  for (int s = 64; s > 0; s >>= 1) {
    if (d < s) red[d] = fmaxf(red[d], red[d + s]);
    __syncthreads();
  }
  float mx = red[0];
  __syncthreads();
  float ex = expf(acc - mx);
  red[d] = ex;
  __syncthreads();
  for (int s = 64; s > 0; s >>= 1) {
    if (d < s) red[d] += red[d + s];
    __syncthreads();
  }
  a_out[b * 128 + d] = ex / red[0];
}

// ---------------- K_xhat: x_hat[t*512+b][d*16+f] = a[b,d]*x[b,t,d,f] (bf16)
__global__ __launch_bounds__(256) void k_xhat(const float* __restrict__ in,
                                              const float* __restrict__ a,
                                              unsigned short* __restrict__ xh) {
  const int mrow = blockIdx.x;            // t*512 + b
  const int t = mrow >> 9, b = mrow & 511;
  const int tid = threadIdx.x;
  const int k = tid * 8;
  const int d = k >> 4;
  const int f0 = k & 15;
  const float* src = in + (((long)(b * 48 + t) * 128 + d) * 16 + f0);
  float4 v0 = *(const float4*)src;
  float4 v1 = *(const float4*)(src + 4);
  float s = a[b * 128 + d];
  u16x8 o;
  o[0] = f2bf(v0.x * s); o[1] = f2bf(v0.y * s); o[2] = f2bf(v0.z * s); o[3] = f2bf(v0.w * s);
  o[4] = f2bf(v1.x * s); o[5] = f2bf(v1.y * s); o[6] = f2bf(v1.z * s); o[7] = f2bf(v1.w * s);
  *(u16x8*)(xh + (long)mrow * 2048 + k) = o;
}

// ---------------- K_gemm: 256x256 pipelined bf16 MFMA GEMM ----------------
// Round-3 version (best measured; MfmaUtil ~45%, conflicts 0). See round-3
// notes: full-BK 128B LDS rows, 3-bit XOR swizzle applied at the global
// source, one barrier + one vmcnt(0) gate per K-tile, ds_reads drain under
// MFMA via compiler-counted lgkmcnt.

#define G_STAGE(ktv, s)                                                         \
  do {                                                                          \
    const long ko_ = (long)(ktv) * 64 + (long)(s) * 262144;                     \
    char* la_ = (char*)SM + ((ktv) & 1) * 32768 + (s) * 16384 + ldsw;           \
    g2lds16(Ag + ko_, la_);                                                     \
    g2lds16(Ag + ko_ + 131072, la_ + 8192);                                     \
    g2lds16(Bg + ko_, la_ + 65536);                                             \
    g2lds16(Bg + ko_ + 131072, la_ + 73728);                                    \
  } while (0)

#define G_LDA4(dst, bufel, ksv, mh)                                             \
  do {                                                                          \
    const unsigned short* ab_ =                                                 \
        SM + (bufel) + aBase + (mh) * 4096 + (psw ^ ((ksv) * 32));              \
    dst[0] = *(const s16x8*)(ab_);                                              \
    dst[1] = *(const s16x8*)(ab_ + 1024);                                       \
    dst[2] = *(const s16x8*)(ab_ + 2048);                                       \
    dst[3] = *(const s16x8*)(ab_ + 3072);                                       \
  } while (0)

#define G_LDB4(dst, bufel, ksv)                                                 \
  do {                                                                          \
    const unsigned short* bb_ = SM + (bufel) + bBase + (psw ^ ((ksv) * 32));    \
    dst[0] = *(const s16x8*)(bb_);                                              \
    dst[1] = *(const s16x8*)(bb_ + 1024);                                       \
    dst[2] = *(const s16x8*)(bb_ + 2048);                                       \
    dst[3] = *(const s16x8*)(bb_ + 3072);                                       \
  } while (0)

#define G_MMA2(mh, Af, Bf)                                                      \
  do {                                                                          \
    __builtin_amdgcn_s_setprio(1);                                              \
    _Pragma("unroll") for (int mt_ = 0; mt_ < 4; ++mt_)                         \
        _Pragma("unroll") for (int nt_ = 0; nt_ < 4; ++nt_)                     \
            acc[(mh) * 4 + mt_][nt_] = __builtin_amdgcn_mfma_f32_16x16x32_bf16( \
                Af[mt_], Bf[nt_], acc[(mh) * 4 + mt_][nt_], 0, 0, 0);           \
    __builtin_amdgcn_s_setprio(0);                                              \
  } while (0)

#define G_GATE(n) asm volatile("s_waitcnt vmcnt(" #n ")" ::: "memory")

__global__ __launch_bounds__(512, 2) void k_gemm(const unsigned short* __restrict__ A,
                                                 const unsigned short* __restrict__ Bw,
                                                 unsigned short* __restrict__ C) {
  __shared__ __align__(16) unsigned short SM[65536];  // A bytes [0,64K), B [64K,128K)
  const int tid = threadIdx.x;
  const int w = tid >> 6, lane = tid & 63;
  const int q = lane >> 4, l16 = lane & 15;
  const int wm = w >> 2, wn = w & 3;
  const int id = blockIdx.x;
  const int xcd = id & 7, j = id >> 3;                 // 768 = 8 XCD * 96, bijective
  const long m0 = ((long)xcd * 12 + (j >> 3)) * 256;   // 96 m-tiles
  const long n0 = (long)(j & 7) * 256;                 // 8 n-tiles, fastest

  const int srow = w * 8 + (lane >> 3);
  const int csrc = (lane & 7) ^ (lane >> 3);
  const unsigned short* Ag = A + (m0 + srow) * 2048 + csrc * 8;
  const unsigned short* Bg = Bw + (n0 + srow) * 2048 + csrc * 8;
  const int ldsw = w * 1024;                           // wave-uniform LDS base

  const int psw = (q ^ (l16 & 7)) * 8;                 // ks1: psw ^ 32
  const int aBase = (wm * 128 + l16) * 64;             // + mh*4096 + mt*1024
  const int bBase = 32768 + (wn * 64 + l16) * 64;      // + nt*1024

  f32x4 acc[8][4];
  const f32x4 zz = {0.f, 0.f, 0.f, 0.f};
#pragma unroll
  for (int i = 0; i < 8; ++i)
#pragma unroll
    for (int j2 = 0; j2 < 4; ++j2) acc[i][j2] = zz;

  G_STAGE(0, 0);
  G_STAGE(0, 1);
  G_GATE(0);
  __builtin_amdgcn_s_barrier();

#pragma unroll 1
  for (int kt = 0; kt < 31; ++kt) {
    const int bufel = (kt & 1) * 16384;
    s16x8 b0[4], b1[4], a00[4], a01[4], a10[4], a11[4];
    G_LDB4(b0, bufel, 0);
    G_LDA4(a00, bufel, 0, 0);
    G_STAGE(kt + 1, 0);
    G_LDA4(a01, bufel, 0, 1);
    G_STAGE(kt + 1, 1);
    G_MMA2(0, a00, b0);          // ph0; a01/b1/a10 reads drain under MFMA
    G_LDB4(b1, bufel, 1);
    G_LDA4(a10, bufel, 1, 0);
    G_MMA2(1, a01, b0);          // ph1
    G_LDA4(a11, bufel, 1, 1);
    G_MMA2(0, a10, b1);          // ph2
    G_MMA2(1, a11, b1);          // ph3
    G_GATE(0);                   // tile kt+1 staged (8 loads this tile)
    __builtin_amdgcn_s_barrier();
  }
  {  // kt = 31 (buf 1): drain tile, no staging
    s16x8 b0[4], b1[4], a00[4], a01[4], a10[4], a11[4];
    G_LDB4(b0, 16384, 0);
    G_LDA4(a00, 16384, 0, 0);
    G_LDA4(a01, 16384, 0, 1);
    G_MMA2(0, a00, b0);
    G_LDB4(b1, 16384, 1);
    G_LDA4(a10, 16384, 1, 0);
    G_MMA2(1, a01, b0);
    G_LDA4(a11, 16384, 1, 1);
    G_MMA2(0, a10, b1);
    G_MMA2(1, a11, b1);
  }

#pragma unroll
  for (int mh = 0; mh < 2; ++mh)
#pragma unroll
    for (int mt = 0; mt < 4; ++mt)
#pragma unroll
      for (int nt = 0; nt < 4; ++nt)
#pragma unroll
        for (int r = 0; r < 4; ++r) {
          long m = m0 + wm * 128 + mh * 64 + mt * 16 + q * 4 + r;
          long n = n0 + wn * 64 + nt * 16 + l16;
          C[m * 2048 + n] = f2bf(acc[mh * 4 + mt][nt][r]);
        }
}

// ---------------- K_rec: persistent LSTM scan (round-6) --------------------
// Keeps round-4 wave-K-split + VGPR-pinned w_hh. Round-6 fixes the two
// latency leaks the counters exposed:
// (1) ALL 4 chunks' h loads issued upfront (16 u64, one compiler-counted
//     vmcnt wait) -- L3 latency paid once (~600cy) not 4x (~2400cy/step).
// (2) pointwise ownership back to (row pm, cols pr0..pr0+3): h publish is
//     ONE u64 sys-store/thread (was 4 scalar u16), out is one f32x4 nt-store
//     -- shortens the pre-flag vmcnt(0) drain on the critical path.
// slab pad 37 (stride == 5 mod 32): scalar reads <=2-way (free); f32x4
// writes (5*l16 mod 32 distinct) <=2-way. hs_own pad 40.
__global__ __launch_bounds__(256, 1) void k_rec(const unsigned short* __restrict__ gx,
                                                const unsigned short* __restrict__ whh_b,
                                                const float* __restrict__ b_ih,
                                                const float* __restrict__ b_hh,
                                                unsigned short* __restrict__ h_buf,
                                                float* __restrict__ out,
                                                unsigned int* __restrict__ bar) {
  __shared__ __align__(16) float slab[16 * 32 * 37];      // 75776 B
  __shared__ __align__(16) unsigned short hs_own[32 * 40];// own h slice mirror
  const int tid = threadIdx.x;
  const int w = tid >> 6, lane = tid & 63;
  const int q = lane >> 4, l16 = lane & 15;
  const int bt = blockIdx.x & 15, g = blockIdx.x >> 4;
  const int b0 = bt * 32;
  const int pm = tid >> 3;              // pointwise: row b0+pm
  const int pr0 = (tid & 7) * 4;        // pointwise: cols g*32+pr0..+3
  unsigned int* slots = &bar[bt * 16];
  const int ownw = ((g >> 2) == w);     // this wave's range contains chunk g
  const int ownc = g & 3;

  // w_hh fragments -> registers, once, via volatile asm loads (VGPR-pinned)
  s16x8 wreg[32];  // [(quad*2+nt)*4 + ci]
#pragma unroll
  for (int quad = 0; quad < 4; ++quad)
#pragma unroll
    for (int nt = 0; nt < 2; ++nt)
#pragma unroll
      for (int ci = 0; ci < 4; ++ci) {
        const unsigned short* wp =
            whh_b + (long)(quad * 512 + g * 32 + nt * 16 + l16) * 512 + (w * 4 + ci) * 32 + q * 8;
        asm volatile("global_load_dwordx4 %0, %1, off"
                     : "=v"(wreg[(quad * 2 + nt) * 4 + ci]) : "v"(wp) : "memory");
      }
  asm volatile("s_waitcnt vmcnt(0)" ::: "memory");
  __builtin_amdgcn_sched_barrier(0);

  float bias_[16];  // [qq*4+rr]
#pragma unroll
  for (int qq = 0; qq < 4; ++qq)
#pragma unroll
    for (int rr = 0; rr < 4; ++rr) {
      int jj = qq * 512 + g * 32 + pr0 + rr;
      bias_[qq * 4 + rr] = b_ih[jj] + b_hh[jj];
    }
  float creg[4] = {0.f, 0.f, 0.f, 0.f};
  const f32x4 zz = {0.f, 0.f, 0.f, 0.f};

  for (int t = 0; t < 48; ++t) {
    // gx prefetch: 4 x u16x4 (8B vector loads), before any waiting
    u16x4 gxr[4];
    const unsigned short* gp = gx + ((long)t * 512 + b0 + pm) * 2048 + g * 32 + pr0;
#pragma unroll
    for (int qq = 0; qq < 4; ++qq) gxr[qq] = *(const u16x4*)(gp + qq * 512);

    if (t > 0) {
      // wait this wave's producer flags (lanes 0..3 poll; own chunk exempt)
      const int need = (lane < 4) && !(ownw && lane == ownc);
      const unsigned* fp = &slots[w * 4 + (lane & 3)];
      while (1) {
        unsigned v = need ? ld_sys_u32(fp) : 0xffffffffu;
        if (__all((int)(v >= (unsigned)t))) break;
      }
      // issue ALL chunk loads upfront; compiler emits counted vmcnt waits
      u64 L[4][4];
      const u64* hb = (const u64*)(h_buf + ((t - 1) & 1) * (512 * 512));
      const long hbase = (long)(b0 + l16) * 128 + q * 2;
#pragma unroll
      for (int ci = 0; ci < 4; ++ci) {
        if (!(ownw && ci == ownc)) {
          long o_ = hbase + (w * 4 + ci) * 8;
          L[ci][0] = ld_sys_u64(hb + o_);
          L[ci][1] = ld_sys_u64(hb + o_ + 1);
          L[ci][2] = ld_sys_u64(hb + o_ + 2048);
          L[ci][3] = ld_sys_u64(hb + o_ + 2049);
        }
      }
      f32x4 acc[4][2][2];
#pragma unroll
      for (int a = 0; a < 4; ++a)
#pragma unroll
        for (int b = 0; b < 2; ++b)
#pragma unroll
          for (int c = 0; c < 2; ++c) acc[a][b][c] = zz;
#pragma unroll
      for (int ci = 0; ci < 4; ++ci) {
        s16x8 af0, af1;
        if (ownw && ci == ownc) {
          af0 = *(const s16x8*)&hs_own[l16 * 40 + q * 8];
          af1 = *(const s16x8*)&hs_own[(16 + l16) * 40 + q * 8];
        } else {
          union { u64 u[2]; s16x8 v; } c0, c1;
          c0.u[0] = L[ci][0]; c0.u[1] = L[ci][1];
          c1.u[0] = L[ci][2]; c1.u[1] = L[ci][3];
          af0 = c0.v; af1 = c1.v;
        }
#pragma unroll
        for (int quad = 0; quad < 4; ++quad)
#pragma unroll
          for (int nt = 0; nt < 2; ++nt) {
            acc[quad][nt][0] = __builtin_amdgcn_mfma_f32_16x16x32_bf16(
                af0, wreg[(quad * 2 + nt) * 4 + ci], acc[quad][nt][0], 0, 0, 0);
            acc[quad][nt][1] = __builtin_amdgcn_mfma_f32_16x16x32_bf16(
                af1, wreg[(quad * 2 + nt) * 4 + ci], acc[quad][nt][1], 0, 0, 0);
          }
      }
      // partials -> slab (f32x4 over rows; pad 37 -> <=2-way on write)
#pragma unroll
      for (int quad = 0; quad < 4; ++quad)
#pragma unroll
        for (int nt = 0; nt < 2; ++nt)
#pragma unroll
          for (int mh = 0; mh < 2; ++mh)
            *(f32x4*)&slab[((w * 4 + quad) * 32 + nt * 16 + l16) * 37 + mh * 16 + q * 4] =
                acc[quad][nt][mh];
    }
    __syncthreads();

    // pointwise: thread owns (row b0+pm, cols g*32+pr0..+3)
    float hval[4];
#pragma unroll
    for (int rr = 0; rr < 4; ++rr) {
      float gv[4];
#pragma unroll
      for (int qq = 0; qq < 4; ++qq) {
        float s = 0.f;
        if (t > 0) {
#pragma unroll
          for (int ws = 0; ws < 4; ++ws)
            s += slab[((ws * 4 + qq) * 32 + pr0 + rr) * 37 + pm];
        }
        gv[qq] = s + bias_[qq * 4 + rr] + bf2f(gxr[qq][rr]);
      }
      float is = fsig(gv[0]);
      float fs = fsig(gv[1]);
      float gt = ftanh(gv[2]);
      float os = fsig(gv[3]);
      creg[rr] = fs * creg[rr] + is * gt;
      hval[rr] = os * ftanh(creg[rr]);
    }
    // publish h: one u64 sys-store (L3) + LDS mirror write
    u16x4 hb4 = {f2bf(hval[0]), f2bf(hval[1]), f2bf(hval[2]), f2bf(hval[3])};
    u64 h8;
    __builtin_memcpy(&h8, &hb4, 8);
    st_sys_u64((u64*)&h_buf[(t & 1) * (512 * 512) + (b0 + pm) * 512 + g * 32 + pr0], h8);
    *(u16x4*)&hs_own[pm * 40 + pr0] = hb4;
    __syncthreads();   // drains vmcnt(0): h stores at L3 before flag
    if (t < 47 && tid == 0)
      st_sys_u32(&slots[g], (unsigned)(t + 1));
    // out store AFTER flag publish (drain overlaps next step's poll)
    f32x4 ov = {hval[0], hval[1], hval[2], hval[3]};
    __builtin_nontemporal_store(ov, (f32x4*)&out[(long)(b0 + pm) * (T_ * H_) + (long)t * H_ + g * 32 + pr0]);
  }
}

extern "C" void kernel_launch(void* const* d_in, const int* in_sizes, int n_in,
                              void* d_out, int out_size, void* d_ws, size_t ws_size,
                              hipStream_t stream) {
  const float* input  = (const float*)d_in[0];
  const float* attn_w = (const float*)d_in[1];
  const float* attn_b = (const float*)d_in[2];
  const float* w_ih   = (const float*)d_in[3];
  const float* w_hh   = (const float*)d_in[4];
  const float* b_ih   = (const float*)d_in[5];
  const float* b_hh   = (const float*)d_in[6];
  float* out = (float*)d_out;

  char* ws = (char*)d_ws;
  unsigned int* bar     = (unsigned int*)ws;                   // [0, 1024)
  float* a_ws           = (float*)(ws + 1024);                 // 512*128*4    = 262144
  unsigned short* h_buf = (unsigned short*)(ws + 263168);      // 2*512*512*2  = 1048576
  unsigned short* whh_b = (unsigned short*)(ws + 1311744);     // 2048*512*2   = 2097152
  unsigned short* wih_b = (unsigned short*)(ws + 3408896);     // 2048*2048*2  = 8388608
  unsigned short* x_hat = (unsigned short*)(ws + 11797504);    // 24576*2048*2 = 100663296
  unsigned short* gxws  = (unsigned short*)(ws + 112460800);   // 24576*2048*2 = 100663296
  float* e_part         = (float*)x_hat;                       // 512*4*128*4 = 1 MB,
                                                               // dead before k_xhat writes

  (void)hipMemsetAsync(d_ws, 0, 1024, stream);
  hipLaunchKernelGGL(k_prep, dim3(5120), dim3(256), 0, stream, w_ih, w_hh, wih_b, whh_b);
  hipLaunchKernelGGL(k_ex1, dim3(2048), dim3(256), 0, stream, input, attn_w, e_part);
  hipLaunchKernelGGL(k_ex2, dim3(512), dim3(128), 0, stream, e_part, attn_b, a_ws);
  hipLaunchKernelGGL(k_xhat, dim3(24576), dim3(256), 0, stream, input, a_ws, x_hat);
  hipLaunchKernelGGL(k_gemm, dim3(768), dim3(512), 0, stream, x_hat, wih_b, gxws);
  hipLaunchKernelGGL(k_rec, dim3(256), dim3(256), 0, stream, gxws, whh_b, b_ih, b_hh, h_buf, out, bar);
}

// Round 7
// 701.735 us; speedup vs baseline: 1.0993x; 1.0993x over previous
//
#include <hip/hip_runtime.h>

#define B_ 512
#define T_ 48
#define D_ 128
#define F_ 16
#define H_ 512
// K = D_*F_ = 2048, gates = 4*H_ = 2048, M = T_*B_ = 24576

typedef float f32x4 __attribute__((ext_vector_type(4)));
typedef short s16x8 __attribute__((ext_vector_type(8)));
typedef unsigned short u16x8 __attribute__((ext_vector_type(8)));
typedef unsigned short u16x4 __attribute__((ext_vector_type(4)));
typedef unsigned long long u64;

__device__ __forceinline__ unsigned short f2bf(float x) {
  unsigned u = __float_as_uint(x);
  u += 0x7fffu + ((u >> 16) & 1u);   // round-to-nearest-even
  return (unsigned short)(u >> 16);
}
__device__ __forceinline__ float bf2f(unsigned short h) {
  return __uint_as_float(((unsigned)h) << 16);
}
// fast sigmoid/tanh via v_exp_f32 (exp2) + v_rcp_f32 (~1ulp; adds ~1e-6 rel err)
__device__ __forceinline__ float fsig(float x) {
  float e = __builtin_amdgcn_exp2f(-1.442695041f * x);
  return __builtin_amdgcn_rcpf(1.f + e);
}
__device__ __forceinline__ float ftanh(float x) {
  float e = __builtin_amdgcn_exp2f(2.885390082f * x);
  return 1.f - 2.f * __builtin_amdgcn_rcpf(1.f + e);
}

// Relaxed system-scope (sc0 sc1) accesses: bypass L1/L2, coherent at L3.
__device__ __forceinline__ void st_sys_u64(u64* p, u64 v) {
  __hip_atomic_store(p, v, __ATOMIC_RELAXED, __HIP_MEMORY_SCOPE_SYSTEM);
}
__device__ __forceinline__ u64 ld_sys_u64(const u64* p) {
  return __hip_atomic_load((u64*)p, __ATOMIC_RELAXED, __HIP_MEMORY_SCOPE_SYSTEM);
}
__device__ __forceinline__ void st_sys_u32(unsigned* p, unsigned v) {
  __hip_atomic_store(p, v, __ATOMIC_RELAXED, __HIP_MEMORY_SCOPE_SYSTEM);
}
__device__ __forceinline__ unsigned ld_sys_u32(const unsigned* p) {
  return __hip_atomic_load((unsigned*)p, __ATOMIC_RELAXED, __HIP_MEMORY_SCOPE_SYSTEM);
}

#define AS1 __attribute__((address_space(1)))
#define AS3 __attribute__((address_space(3)))
__device__ __forceinline__ void g2lds16(const void* g, void* l) {
  __builtin_amdgcn_global_load_lds((const AS1 void*)g, (AS3 void*)l, 16, 0, 0);
}

// ---------------- K_prep: fp32 -> bf16 weight conversion ----------------
__global__ __launch_bounds__(256) void k_prep(const float* __restrict__ wih,
                                              const float* __restrict__ whh,
                                              unsigned short* __restrict__ wih_b,
                                              unsigned short* __restrict__ whh_b) {
  long i4 = ((long)blockIdx.x * 256 + threadIdx.x) * 4;
  if (i4 < 4194304) {
    float4 v = *(const float4*)(wih + i4);
    u16x4 o = {f2bf(v.x), f2bf(v.y), f2bf(v.z), f2bf(v.w)};
    *(u16x4*)(wih_b + i4) = o;
  } else {
    long j = i4 - 4194304;
    if (j < 1048576) {
      float4 v = *(const float4*)(whh + j);
      u16x4 o = {f2bf(v.x), f2bf(v.y), f2bf(v.z), f2bf(v.w)};
      *(u16x4*)(whh_b + j) = o;
    }
  }
}

// ---------------- K_ex1: partial e_x sums, full-occupancy streaming -------
__global__ __launch_bounds__(256) void k_ex1(const float* __restrict__ in,
                                             const float* __restrict__ attn_w,
                                             float* __restrict__ e_part) {
  __shared__ float wx[768];
  const int bc = blockIdx.x;            // b*4 + c
  const int b = bc >> 2, c = bc & 3;
  const int tid = threadIdx.x;
  const int d = tid >> 1, fh = tid & 1;
  for (int i = tid; i < 768; i += 256) wx[i] = attn_w[1024 + i];
  __syncthreads();
  const float* base = in + (long)b * 98304 + (long)d * 16 + fh * 8;
  float acc = 0.f;
  for (int t = c * 12; t < c * 12 + 12; ++t) {
    const float4* p = (const float4*)(base + (long)t * 2048);
    float4 v0 = p[0], v1 = p[1];
    const float* wt = wx + fh * 384 + t;
    acc += v0.x * wt[0]   + v0.y * wt[48]  + v0.z * wt[96]  + v0.w * wt[144];
    acc += v1.x * wt[192] + v1.y * wt[240] + v1.z * wt[288] + v1.w * wt[336];
  }
  acc += __shfl_xor(acc, 1);
  if (fh == 0) e_part[(long)bc * 128 + d] = acc;
}

// ---------------- K_ex2: combine partials + softmax over D ---------------
__global__ __launch_bounds__(128) void k_ex2(const float* __restrict__ e_part,
                                             const float* __restrict__ attn_b,
                                             float* __restrict__ a_out) {
  __shared__ float red[128];
  const int b = blockIdx.x, d = threadIdx.x;
  float acc = attn_b[0];
  for (int c = 0; c < 4; ++c) acc += e_part[(long)(b * 4 + c) * 128 + d];
  red[d] = acc;
  __syncthreads();
  for (int s = 64; s > 0; s >>= 1) {
    if (d < s) red[d] = fmaxf(red[d], red[d + s]);
    __syncthreads();
  }
  float mx = red[0];
  __syncthreads();
  float ex = expf(acc - mx);
  red[d] = ex;
  __syncthreads();
  for (int s = 64; s > 0; s >>= 1) {
    if (d < s) red[d] += red[d + s];
    __syncthreads();
  }
  a_out[b * 128 + d] = ex / red[0];
}

// ---------------- K_xhat: x_hat[t*512+b][d*16+f] = a[b,d]*x[b,t,d,f] (bf16)
__global__ __launch_bounds__(256) void k_xhat(const float* __restrict__ in,
                                              const float* __restrict__ a,
                                              unsigned short* __restrict__ xh) {
  const int mrow = blockIdx.x;            // t*512 + b
  const int t = mrow >> 9, b = mrow & 511;
  const int tid = threadIdx.x;
  const int k = tid * 8;
  const int d = k >> 4;
  const int f0 = k & 15;
  const float* src = in + (((long)(b * 48 + t) * 128 + d) * 16 + f0);
  float4 v0 = *(const float4*)src;
  float4 v1 = *(const float4*)(src + 4);
  float s = a[b * 128 + d];
  u16x8 o;
  o[0] = f2bf(v0.x * s); o[1] = f2bf(v0.y * s); o[2] = f2bf(v0.z * s); o[3] = f2bf(v0.w * s);
  o[4] = f2bf(v1.x * s); o[5] = f2bf(v1.y * s); o[6] = f2bf(v1.z * s); o[7] = f2bf(v1.w * s);
  *(u16x8*)(xh + (long)mrow * 2048 + k) = o;
}

// ---------------- K_gemm: 256x256 pipelined bf16 MFMA GEMM ----------------
// Round-7: same data path as round-3 (verified: conflicts == 0), new intra-
// tile schedule killing the post-barrier cold start. Per tile: stage kt+1 at
// loop TOP (buffer freed by prev barrier); 4 MFMA phases; gate
// (vmcnt(0)+lgkmcnt(0)) + barrier moved BEFORE the last MFMA cluster; next
// tile's ph0 fragments (na0/nb0) prefetched right after the barrier so the
// final cluster covers their latency and every tile's ph0 starts with
// operands in registers. Lifetimes: buf^1 staged at top-of-kt was last read
// before kt-1's barrier (lgkmcnt(0) drained); prefetch reads buf^1 after
// gate+barrier => all waves' stages landed; a11/b1 are in regs (lgkmcnt(0))
// before other waves can overwrite buf kt at their next loop top.

#define G_STAGE(ktv, s)                                                         \
  do {                                                                          \
    const long ko_ = (long)(ktv) * 64 + (long)(s) * 262144;                     \
    char* la_ = (char*)SM + ((ktv) & 1) * 32768 + (s) * 16384 + ldsw;           \
    g2lds16(Ag + ko_, la_);                                                     \
    g2lds16(Ag + ko_ + 131072, la_ + 8192);                                     \
    g2lds16(Bg + ko_, la_ + 65536);                                             \
    g2lds16(Bg + ko_ + 131072, la_ + 73728);                                    \
  } while (0)

#define G_LDA4(dst, bufel, ksv, mh)                                             \
  do {                                                                          \
    const unsigned short* ab_ =                                                 \
        SM + (bufel) + aBase + (mh) * 4096 + (psw ^ ((ksv) * 32));              \
    dst[0] = *(const s16x8*)(ab_);                                              \
    dst[1] = *(const s16x8*)(ab_ + 1024);                                       \
    dst[2] = *(const s16x8*)(ab_ + 2048);                                       \
    dst[3] = *(const s16x8*)(ab_ + 3072);                                       \
  } while (0)

#define G_LDB4(dst, bufel, ksv)                                                 \
  do {                                                                          \
    const unsigned short* bb_ = SM + (bufel) + bBase + (psw ^ ((ksv) * 32));    \
    dst[0] = *(const s16x8*)(bb_);                                              \
    dst[1] = *(const s16x8*)(bb_ + 1024);                                       \
    dst[2] = *(const s16x8*)(bb_ + 2048);                                       \
    dst[3] = *(const s16x8*)(bb_ + 3072);                                       \
  } while (0)

#define G_MMA2(mh, Af, Bf)                                                      \
  do {                                                                          \
    __builtin_amdgcn_s_setprio(1);                                              \
    _Pragma("unroll") for (int mt_ = 0; mt_ < 4; ++mt_)                         \
        _Pragma("unroll") for (int nt_ = 0; nt_ < 4; ++nt_)                     \
            acc[(mh) * 4 + mt_][nt_] = __builtin_amdgcn_mfma_f32_16x16x32_bf16( \
                Af[mt_], Bf[nt_], acc[(mh) * 4 + mt_][nt_], 0, 0, 0);           \
    __builtin_amdgcn_s_setprio(0);                                              \
  } while (0)

__global__ __launch_bounds__(512, 2) void k_gemm(const unsigned short* __restrict__ A,
                                                 const unsigned short* __restrict__ Bw,
                                                 unsigned short* __restrict__ C) {
  __shared__ __align__(16) unsigned short SM[65536];  // A bytes [0,64K), B [64K,128K)
  const int tid = threadIdx.x;
  const int w = tid >> 6, lane = tid & 63;
  const int q = lane >> 4, l16 = lane & 15;
  const int wm = w >> 2, wn = w & 3;
  const int id = blockIdx.x;
  const int xcd = id & 7, j = id >> 3;                 // 768 = 8 XCD * 96, bijective
  const long m0 = ((long)xcd * 12 + (j >> 3)) * 256;   // 96 m-tiles
  const long n0 = (long)(j & 7) * 256;                 // 8 n-tiles, fastest

  const int srow = w * 8 + (lane >> 3);
  const int csrc = (lane & 7) ^ (lane >> 3);
  const unsigned short* Ag = A + (m0 + srow) * 2048 + csrc * 8;
  const unsigned short* Bg = Bw + (n0 + srow) * 2048 + csrc * 8;
  const int ldsw = w * 1024;                           // wave-uniform LDS base

  const int psw = (q ^ (l16 & 7)) * 8;                 // ks1: psw ^ 32
  const int aBase = (wm * 128 + l16) * 64;             // + mh*4096 + mt*1024
  const int bBase = 32768 + (wn * 64 + l16) * 64;      // + nt*1024

  f32x4 acc[8][4];
  const f32x4 zz = {0.f, 0.f, 0.f, 0.f};
#pragma unroll
  for (int i = 0; i < 8; ++i)
#pragma unroll
    for (int j2 = 0; j2 < 4; ++j2) acc[i][j2] = zz;

  s16x8 na0[4], nb0[4];
  // prologue: stage tile 0, drain (cold), barrier, prefetch ph0 frags
  G_STAGE(0, 0);
  G_STAGE(0, 1);
  asm volatile("s_waitcnt vmcnt(0)" ::: "memory");
  __builtin_amdgcn_s_barrier();
  G_LDB4(nb0, 0, 0);
  G_LDA4(na0, 0, 0, 0);

#pragma unroll 1
  for (int kt = 0; kt < 31; ++kt) {
    const int bufel = (kt & 1) * 16384;
    s16x8 b1[4], a01[4], a10[4], a11[4];
    G_STAGE(kt + 1, 0);                // into buf^1 (freed by prev barrier)
    G_STAGE(kt + 1, 1);
    G_MMA2(0, na0, nb0);               // ph0 (operands already in regs)
    G_LDA4(a01, bufel, 0, 1);
    G_MMA2(1, a01, nb0);               // ph1
    G_LDB4(b1, bufel, 1);
    G_LDA4(a10, bufel, 1, 0);
    G_MMA2(0, a10, b1);                // ph2
    G_LDA4(a11, bufel, 1, 1);
    asm volatile("s_waitcnt vmcnt(0) lgkmcnt(0)" ::: "memory"); // stages + a11 done
    __builtin_amdgcn_s_barrier();      // buf^1 fully staged; buf kt reads all done
    G_LDB4(nb0, bufel ^ 16384, 0);     // prefetch next tile ph0
    G_LDA4(na0, bufel ^ 16384, 0, 0);
    G_MMA2(1, a11, b1);                // ph3 covers prefetch latency
  }
  {  // kt = 31 (buf 1): drain tile, no staging
    s16x8 b1[4], a01[4], a10[4], a11[4];
    G_MMA2(0, na0, nb0);
    G_LDA4(a01, 16384, 0, 1);
    G_MMA2(1, a01, nb0);
    G_LDB4(b1, 16384, 1);
    G_LDA4(a10, 16384, 1, 0);
    G_MMA2(0, a10, b1);
    G_LDA4(a11, 16384, 1, 1);
    G_MMA2(1, a11, b1);
  }

  // epilogue: C[m][n], row = m0 + wm*128 + mh*64 + mt*16 + q*4 + r, col += l16
#pragma unroll
  for (int mh = 0; mh < 2; ++mh)
#pragma unroll
    for (int mt = 0; mt < 4; ++mt)
#pragma unroll
      for (int nt = 0; nt < 4; ++nt)
#pragma unroll
        for (int r = 0; r < 4; ++r) {
          long m = m0 + wm * 128 + mh * 64 + mt * 16 + q * 4 + r;
          long n = n0 + wn * 64 + nt * 16 + l16;
          C[m * 2048 + n] = f2bf(acc[mh * 4 + mt][nt][r]);
        }
}

// ---------------- K_rec: persistent LSTM scan (round-3 skeleton + fixes) ---
// block (bt,g): bt = blockIdx&15, g = blockIdx>>4. Wave == gate quadrant.
// Round-7 fixes on the measured-200us round-3 structure:
// (1) hs uses the gemm-verified XOR-chunk layout: linear [32][512] rows,
//     16B chunk at position c^(row&7) — staging writes and fragment reads
//     both apply the XOR (kills the ~1e7 b128 read conflicts).
// (2) w_hh fragments via volatile asm global_load_dwordx4 — pinned VGPR-
//     resident (round-3's VGPR=120 < 128 proved they were refetched from L2
//     inside the serial MFMA chain every step).
// (3) fast fsig/ftanh (validated rounds 4-6, absmax unchanged).
__global__ __launch_bounds__(256, 1) void k_rec(const unsigned short* __restrict__ gx,
                                                const unsigned short* __restrict__ whh_b,
                                                const float* __restrict__ b_ih,
                                                const float* __restrict__ b_hh,
                                                unsigned short* __restrict__ h_buf,
                                                float* __restrict__ out,
                                                unsigned int* __restrict__ bar) {
  __shared__ __align__(16) unsigned short hs[32 * 512];  // XOR-chunk layout, 32KB
  __shared__ float gsm[4 * 32 * 37];        // [quad][colN 32][rowM pad37]
  const int tid = threadIdx.x;
  const int wave = tid >> 6, lane = tid & 63;   // wave == gate quadrant
  const int q = lane >> 4, l16 = lane & 15;
  const int bt = blockIdx.x & 15, g = blockIdx.x >> 4;
  const int b0 = bt * 32;
  const int pm = tid >> 3, pr = (tid & 7) * 4;  // pointwise: row pm, cols pr..pr+3
  const int srow = tid >> 3, st7 = tid & 7;     // stage: row srow, u64 lane st7
  const int sxk = srow & 7;                     // stage-row xor key
  const int rxk = l16 & 7;                      // read-row xor key ((16+l16)&7 == l16&7)
  unsigned int* slots = &bar[bt * 16];

  // w_hh fragments -> registers, once, via volatile asm loads (VGPR-pinned)
  s16x8 wreg[32];
#pragma unroll
  for (int nt = 0; nt < 2; ++nt)
#pragma unroll
    for (int kk = 0; kk < 16; ++kk) {
      const unsigned short* wp =
          whh_b + (long)(wave * 512 + g * 32 + nt * 16 + l16) * 512 + kk * 32 + q * 8;
      asm volatile("global_load_dwordx4 %0, %1, off"
                   : "=v"(wreg[nt * 16 + kk]) : "v"(wp) : "memory");
    }
  asm volatile("s_waitcnt vmcnt(0)" ::: "memory");
  __builtin_amdgcn_sched_barrier(0);

  float bias_[16];
#pragma unroll
  for (int qq = 0; qq < 4; ++qq)
#pragma unroll
    for (int rr = 0; rr < 4; ++rr) {
      int jj = qq * 512 + g * 32 + pr + rr;
      bias_[qq * 4 + rr] = b_ih[jj] + b_hh[jj];
    }
  float creg[4] = {0.f, 0.f, 0.f, 0.f};
  const f32x4 zz = {0.f, 0.f, 0.f, 0.f};

  for (int t = 0; t < 48; ++t) {
    // prefetch gx (8B vector loads, issued before any waiting)
    u16x4 gxr[4];
    const unsigned short* gp = gx + ((long)t * 512 + b0 + pm) * 2048 + g * 32 + pr;
#pragma unroll
    for (int qq = 0; qq < 4; ++qq) gxr[qq] = *(const u16x4*)(gp + qq * 512);

    f32x4 acc[2][2] = {{zz, zz}, {zz, zz}};
    if (t > 0) {
      // wait for the 16 producer slots of this bt group (relaxed sys polls)
      if (wave == 0 && lane < 16) {
        while (ld_sys_u32(&slots[lane]) < (unsigned)t)
          __builtin_amdgcn_s_sleep(1);
      }
      __syncthreads();
      // stage h(t-1)[b0:b0+32, 0:512] -> hs, XOR-chunk swizzled
      const u64* hp = (const u64*)(h_buf + ((t - 1) & 1) * (512 * 512) + (long)b0 * 512);
      u64 tmp[16];
#pragma unroll
      for (int j = 0; j < 16; ++j)
        tmp[j] = ld_sys_u64(hp + (long)srow * 128 + st7 + 8 * j);
#pragma unroll
      for (int j = 0; j < 16; ++j) {
        const int idx = st7 + 8 * j;          // u64 index in row, 0..127
        const int c = idx >> 1, half = idx & 1;
        *(u64*)&hs[srow * 512 + ((c ^ sxk) << 3) + (half << 2)] = tmp[j];
      }
      __syncthreads();
#pragma unroll
      for (int kk = 0; kk < 16; ++kk) {
        const int c = 4 * kk + q;
        s16x8 af0 = *(const s16x8*)&hs[l16 * 512 + ((c ^ rxk) << 3)];
        s16x8 af1 = *(const s16x8*)&hs[(16 + l16) * 512 + ((c ^ rxk) << 3)];
        acc[0][0] = __builtin_amdgcn_mfma_f32_16x16x32_bf16(af0, wreg[kk],      acc[0][0], 0, 0, 0);
        acc[0][1] = __builtin_amdgcn_mfma_f32_16x16x32_bf16(af0, wreg[16 + kk], acc[0][1], 0, 0, 0);
        acc[1][0] = __builtin_amdgcn_mfma_f32_16x16x32_bf16(af1, wreg[kk],      acc[1][0], 0, 0, 0);
        acc[1][1] = __builtin_amdgcn_mfma_f32_16x16x32_bf16(af1, wreg[16 + kk], acc[1][1], 0, 0, 0);
      }
    }
    // acc -> gsm[wave][colN][rowM]; rows mt*16+q*4..+3 contiguous => b128 store
#pragma unroll
    for (int mt = 0; mt < 2; ++mt)
#pragma unroll
      for (int nt = 0; nt < 2; ++nt)
        *(f32x4*)&gsm[(wave * 32 + nt * 16 + l16) * 37 + mt * 16 + q * 4] = acc[mt][nt];
    __syncthreads();
    // pointwise LSTM cell: thread owns (row b0+pm, cols g*32+pr..+3)
    float hval[4];
#pragma unroll
    for (int rr = 0; rr < 4; ++rr) {
      float gv[4];
#pragma unroll
      for (int qq = 0; qq < 4; ++qq)
        gv[qq] = gsm[(qq * 32 + pr + rr) * 37 + pm] + bf2f(gxr[qq][rr]) + bias_[qq * 4 + rr];
      float is = fsig(gv[0]);
      float fs = fsig(gv[1]);
      float gt = ftanh(gv[2]);
      float os = fsig(gv[3]);
      creg[rr] = fs * creg[rr] + is * gt;
      hval[rr] = os * ftanh(creg[rr]);
    }
    // publish h slice via system-scope store (lands in coherent L3)
    u16x4 hb = {f2bf(hval[0]), f2bf(hval[1]), f2bf(hval[2]), f2bf(hval[3])};
    u64 hb8;
    __builtin_memcpy(&hb8, &hb, 8);
    st_sys_u64((u64*)&h_buf[(t & 1) * (512 * 512) + (b0 + pm) * 512 + g * 32 + pr], hb8);
    __syncthreads();   // drains vmcnt(0): h stores at L3 before flag
    if (t < 47 && tid == 0)
      st_sys_u32(&slots[g], (unsigned)(t + 1));
    // out store AFTER the flag publish: drains during the next step's poll
    f32x4 ov = {hval[0], hval[1], hval[2], hval[3]};
    __builtin_nontemporal_store(ov, (f32x4*)&out[(long)(b0 + pm) * (T_ * H_) + (long)t * H_ + g * 32 + pr]);
  }
}

extern "C" void kernel_launch(void* const* d_in, const int* in_sizes, int n_in,
                              void* d_out, int out_size, void* d_ws, size_t ws_size,
                              hipStream_t stream) {
  const float* input  = (const float*)d_in[0];
  const float* attn_w = (const float*)d_in[1];
  const float* attn_b = (const float*)d_in[2];
  const float* w_ih   = (const float*)d_in[3];
  const float* w_hh   = (const float*)d_in[4];
  const float* b_ih   = (const float*)d_in[5];
  const float* b_hh   = (const float*)d_in[6];
  float* out = (float*)d_out;

  char* ws = (char*)d_ws;
  unsigned int* bar     = (unsigned int*)ws;                   // [0, 1024)
  float* a_ws           = (float*)(ws + 1024);                 // 512*128*4    = 262144
  unsigned short* h_buf = (unsigned short*)(ws + 263168);      // 2*512*512*2  = 1048576
  unsigned short* whh_b = (unsigned short*)(ws + 1311744);     // 2048*512*2   = 2097152
  unsigned short* wih_b = (unsigned short*)(ws + 3408896);     // 2048*2048*2  = 8388608
  unsigned short* x_hat = (unsigned short*)(ws + 11797504);    // 24576*2048*2 = 100663296
  unsigned short* gxws  = (unsigned short*)(ws + 112460800);   // 24576*2048*2 = 100663296
  float* e_part         = (float*)x_hat;                       // 1 MB, dead before k_xhat

  (void)hipMemsetAsync(d_ws, 0, 1024, stream);
  hipLaunchKernelGGL(k_prep, dim3(5120), dim3(256), 0, stream, w_ih, w_hh, wih_b, whh_b);
  hipLaunchKernelGGL(k_ex1, dim3(2048), dim3(256), 0, stream, input, attn_w, e_part);
  hipLaunchKernelGGL(k_ex2, dim3(512), dim3(128), 0, stream, e_part, attn_b, a_ws);
  hipLaunchKernelGGL(k_xhat, dim3(24576), dim3(256), 0, stream, input, a_ws, x_hat);
  hipLaunchKernelGGL(k_gemm, dim3(768), dim3(512), 0, stream, x_hat, wih_b, gxws);
  hipLaunchKernelGGL(k_rec, dim3(256), dim3(256), 0, stream, gxws, whh_b, b_ih, b_hh, h_buf, out, bar);
}